// Round 1
// baseline (345.022 us; speedup 1.0000x reference)
//
#include <hip/hip_runtime.h>

// Problem constants (fixed by setup_inputs: B=128, S=524288, target_len=256).
// L = S / target_len = 2048 floats per segment; segments tile flat memory.
#define SEG_LEN 2048
#define GAPS_INV (1.0f / 2047.0f)

__global__ __launch_bounds__(256)
void seg_change_strength_kernel(const float* __restrict__ x,
                                float* __restrict__ out) {
    const int t = threadIdx.x;              // 0..255
    const long long segBase = (long long)blockIdx.x * SEG_LEN;
    const float* p = x + segBase + (long long)t * 8;

    // 8 contiguous elements per thread via two float4 loads (16B aligned:
    // segBase is 8 KiB aligned, t*8 floats = 32 B stride).
    const float4 v0 = *(const float4*)(p);
    const float4 v1 = *(const float4*)(p + 4);
    // 9th element for the cross-thread boundary diff. Last thread of the
    // segment has no 2048th-gap: substitute v1.w so its diff is 0.
    const float nxt = (t < 255) ? p[8] : v1.w;

    float s = fabsf(v0.y - v0.x) + fabsf(v0.z - v0.y) + fabsf(v0.w - v0.z)
            + fabsf(v1.x - v0.w) + fabsf(v1.y - v1.x) + fabsf(v1.z - v1.y)
            + fabsf(v1.w - v1.z) + fabsf(nxt  - v1.w);

    // Wave-64 butterfly reduction.
    #pragma unroll
    for (int off = 32; off > 0; off >>= 1)
        s += __shfl_down(s, off, 64);

    // 4 waves per block -> LDS -> single store.
    __shared__ float wsum[4];
    if ((t & 63) == 0) wsum[t >> 6] = s;
    __syncthreads();
    if (t == 0)
        out[blockIdx.x] = (wsum[0] + wsum[1] + wsum[2] + wsum[3]) * GAPS_INV;
}

extern "C" void kernel_launch(void* const* d_in, const int* in_sizes, int n_in,
                              void* d_out, int out_size, void* d_ws, size_t ws_size,
                              hipStream_t stream) {
    const float* x = (const float*)d_in[0];
    float* out = (float*)d_out;
    const int n = in_sizes[0];              // B * S = 67108864
    const int nseg = n / SEG_LEN;           // B * target_len = 32768 = out_size
    seg_change_strength_kernel<<<nseg, 256, 0, stream>>>(x, out);
}